// Round 1
// baseline (427.253 us; speedup 1.0000x reference)
//
#include <hip/hip_runtime.h>
#include <math.h>

// L=4096, N=16, H=16, E=64. rows = L*N = 65536. data[l][n][h][e] fp32.
// out[l][n][h][f] = exp( sum_e x_e * proj[h,e,f] - 0.5*||x||^2 ) + 1e-6,
//   x = data_row * 64^-0.25, proj from sign-fixed QR of pm[h]^T.

// ---------------- per-head Householder QR (LAPACK geqrf convention), fp64 ----
__global__ __launch_bounds__(64) void qr_kernel(const float* __restrict__ pm,
                                                float* __restrict__ P)
{
    __shared__ double Ad[64 * 65];
    __shared__ double Vd[64 * 65];
    __shared__ double Qd[64 * 65];
    __shared__ double taus[64];
    __shared__ double betas[64];

    const int lane = threadIdx.x;   // 0..63
    const int h    = blockIdx.x;    // 0..15

    // Ad = mat^T : Ad[i][j] = pm[h][j][i]   (coalesced: lane = i)
    for (int k = 0; k < 64; ++k)
        Ad[lane * 65 + k] = (double)pm[h * 4096 + k * 64 + lane];
    __syncthreads();

    // Factor: reflectors into Vd, diag(R) into betas, taus.
    for (int j = 0; j < 64; ++j) {
        double a = Ad[lane * 65 + j];
        double t = (lane > j) ? a * a : 0.0;
        #pragma unroll
        for (int m = 1; m < 64; m <<= 1) t += __shfl_xor(t, m);
        double alpha = __shfl(a, j);
        double v, tauj;
        if (t == 0.0) {                       // LAPACK: xnorm==0 -> H = I
            tauj = 0.0;
            v = (lane == j) ? 1.0 : 0.0;
            if (lane == j) { betas[j] = alpha; taus[j] = 0.0; }
        } else {
            double anorm = sqrt(alpha * alpha + t);
            double beta  = (alpha >= 0.0) ? -anorm : anorm;  // -sign(alpha)*norm
            tauj = (beta - alpha) / beta;
            double scale = 1.0 / (alpha - beta);
            v = (lane == j) ? 1.0 : ((lane > j) ? a * scale : 0.0);
            if (lane == j) { betas[j] = beta; taus[j] = tauj; }
        }
        Vd[lane * 65 + j] = v;
        __syncthreads();
        const int c = lane;                   // lane = trailing column now
        if (c > j && tauj != 0.0) {
            double w0 = 0, w1 = 0, w2 = 0, w3 = 0;
            int i = j;
            for (; i + 3 < 64; i += 4) {
                w0 = fma(Vd[(i    ) * 65 + j], Ad[(i    ) * 65 + c], w0);
                w1 = fma(Vd[(i + 1) * 65 + j], Ad[(i + 1) * 65 + c], w1);
                w2 = fma(Vd[(i + 2) * 65 + j], Ad[(i + 2) * 65 + c], w2);
                w3 = fma(Vd[(i + 3) * 65 + j], Ad[(i + 3) * 65 + c], w3);
            }
            for (; i < 64; ++i) w0 = fma(Vd[i * 65 + j], Ad[i * 65 + c], w0);
            const double tw = tauj * ((w0 + w1) + (w2 + w3));
            for (i = j; i < 64; ++i)
                Ad[i * 65 + c] = fma(-tw, Vd[i * 65 + j], Ad[i * 65 + c]);
        }
        __syncthreads();
    }

    // Q = H_0 (H_1 (... H_63 I))  (reverse accumulation; cols < j stay e_c)
    for (int k = 0; k < 64; ++k)
        Qd[lane * 65 + k] = (lane == k) ? 1.0 : 0.0;
    __syncthreads();
    for (int j = 63; j >= 0; --j) {
        const double tauj = taus[j];
        const int c = lane;
        if (c >= j && tauj != 0.0) {
            double w0 = 0, w1 = 0, w2 = 0, w3 = 0;
            int i = j;
            for (; i + 3 < 64; i += 4) {
                w0 = fma(Vd[(i    ) * 65 + j], Qd[(i    ) * 65 + c], w0);
                w1 = fma(Vd[(i + 1) * 65 + j], Qd[(i + 1) * 65 + c], w1);
                w2 = fma(Vd[(i + 2) * 65 + j], Qd[(i + 2) * 65 + c], w2);
                w3 = fma(Vd[(i + 3) * 65 + j], Qd[(i + 3) * 65 + c], w3);
            }
            for (; i < 64; ++i) w0 = fma(Vd[i * 65 + j], Qd[i * 65 + c], w0);
            const double tw = tauj * ((w0 + w1) + (w2 + w3));
            for (i = j; i < 64; ++i)
                Qd[i * 65 + c] = fma(-tw, Vd[i * 65 + j], Qd[i * 65 + c]);
        }
        __syncthreads();
    }

    // proj[e][f] = Q[f][e] * sign(beta_f); fold in normalizer 64^-0.25.
    const double nz = 0.35355339059327373;    // 2^-1.5
    for (int k = 0; k < 64; ++k) {
        const double dv = (betas[lane] >= 0.0) ? nz : -nz;
        P[h * 4096 + k * 64 + lane] = (float)(Qd[lane * 65 + k] * dv);
    }
}

// ---------------- main FAVOR+ map: (1M x 64) rows x per-head 64x64 ----------
__global__ __launch_bounds__(256) void favor_kernel(const float* __restrict__ data,
                                                    const float* __restrict__ P,
                                                    float* __restrict__ out)
{
    __shared__ float Xs[64 * 68];   // X^T tile: Xs[e*68 + r], 16B-aligned rows
    __shared__ float sq_s[64];      // 0.5*||x||^2 per row

    const int tid  = threadIdx.x;
    const int lane = tid & 63;      // = output feature f
    const int wv   = tid >> 6;      // wave 0..3
    const int h    = blockIdx.x & 15;
    const size_t chunk = blockIdx.x >> 4;      // 0..63

    // P column f=lane of head h, pre-scaled by normalizer (in registers).
    float p[64];
    #pragma unroll
    for (int e = 0; e < 64; ++e)
        p[e] = P[h * 4096 + e * 64 + lane];

    const size_t row0 = chunk * 1024;          // 1024 rows per block, 16 tiles

    for (int t = 0; t < 16; ++t) {
        const size_t rbase = row0 + (size_t)t * 64;
        __syncthreads();                       // protect Xs from prior readers
        // ---- stage 64 rows, transposed, + row sums of squares ----
        #pragma unroll
        for (int k = 0; k < 4; ++k) {
            const int f4id = tid + 256 * k;    // 0..1023
            const int r    = f4id >> 4;        // row 0..63
            const int c    = f4id & 15;        // float4 chunk 0..15
            const size_t row = rbase + (size_t)r;
            const float4 v = reinterpret_cast<const float4*>(data)[row * 256 + h * 16 + c];
            Xs[(4 * c + 0) * 68 + r] = v.x;
            Xs[(4 * c + 1) * 68 + r] = v.y;
            Xs[(4 * c + 2) * 68 + r] = v.z;
            Xs[(4 * c + 3) * 68 + r] = v.w;
            float sqp = v.x * v.x + v.y * v.y + v.z * v.z + v.w * v.w;
            sqp += __shfl_xor(sqp, 1);
            sqp += __shfl_xor(sqp, 2);
            sqp += __shfl_xor(sqp, 4);
            sqp += __shfl_xor(sqp, 8);
            if ((lane & 15) == 0) sq_s[r] = 0.0625f * sqp;  // 0.5 * nz^2 = 1/16
        }
        __syncthreads();
        // ---- compute: wave wv owns rows wv*16 .. wv*16+15, 4 rows/batch ----
        #pragma unroll
        for (int b = 0; b < 4; ++b) {
            const int rb = wv * 16 + b * 4;
            float a0 = 0.f, a1 = 0.f, a2 = 0.f, a3 = 0.f;
            #pragma unroll
            for (int e = 0; e < 64; ++e) {
                const float4 xv = *reinterpret_cast<const float4*>(&Xs[e * 68 + rb]);
                a0 = fmaf(xv.x, p[e], a0);
                a1 = fmaf(xv.y, p[e], a1);
                a2 = fmaf(xv.z, p[e], a2);
                a3 = fmaf(xv.w, p[e], a3);
            }
            const float4 sqv = *reinterpret_cast<const float4*>(&sq_s[rb]);
            const size_t base = ((rbase + (size_t)rb) * 16 + (size_t)h) * 64 + (size_t)lane;
            out[base         ] = __expf(a0 - sqv.x) + 1e-6f;
            out[base + 1024  ] = __expf(a1 - sqv.y) + 1e-6f;
            out[base + 2048  ] = __expf(a2 - sqv.z) + 1e-6f;
            out[base + 3072  ] = __expf(a3 - sqv.w) + 1e-6f;
        }
    }
}

extern "C" void kernel_launch(void* const* d_in, const int* in_sizes, int n_in,
                              void* d_out, int out_size, void* d_ws, size_t ws_size,
                              hipStream_t stream)
{
    const float* data = (const float*)d_in[0];   // (L,N,H,E) fp32
    const float* pm   = (const float*)d_in[1];   // (H,E,E)   fp32
    float* out = (float*)d_out;                  // (L,N,H,F) fp32
    float* P   = (float*)d_ws;                   // 16*64*64*4 = 256 KB scratch

    qr_kernel<<<16, 64, 0, stream>>>(pm, P);
    favor_kernel<<<1024, 256, 0, stream>>>(data, P, out);
}

// Round 3
// 273.885 us; speedup vs baseline: 1.5600x; 1.5600x over previous
//
#include <hip/hip_runtime.h>
#include <math.h>

// L=4096, N=16, H=16, E=64. rows = L*N = 65536. data[l][n][h][e] fp32.
// out[l][n][h][f] = exp( sum_e x_e * proj[h,e,f] - 0.5*||x||^2 ) + 1e-6,
//   x = data_row * 64^-0.25.
// proj = q^T D of QR(pm[h]^T), D = diag(sign(diag(r))) scaling COLUMNS of q^T.
// This is LAPACK-sign-convention DEPENDENT (round-2 lesson): we must reproduce
// geqrf's beta = -sign(alpha)*norm. Factor phase only; Q = M R^-1 by solve.

// ------- per-head Householder factor (LAPACK signs) + solve, fp64 ----------
__global__ __launch_bounds__(256) void qr_kernel(const float* __restrict__ pm,
                                                 float* __restrict__ P)
{
    __shared__ double Ac[64 * 65];   // working matrix, col-major Ac[c*65+i]
    __shared__ double Mc[64 * 65];   // original M, col-major (solve destroys)
    __shared__ double Qc[64 * 65];   // Q, col-major
    __shared__ double vs[64];        // current reflector
    __shared__ double Ws[4 * 64];    // reduction partials
    __shared__ double tau_s;

    const int tid = threadIdx.x;     // 0..255
    const int h   = blockIdx.x;      // 0..15
    const int c   = tid & 63;        // column owned in update phases
    const int q   = tid >> 6;        // row-quarter
    const int i0  = q * 16;

    // load M[i][j] = pm[h][j][i]; col-major Mc[j*65+i]
    #pragma unroll
    for (int kk = 0; kk < 16; ++kk) {
        const int idx = tid + 256 * kk;          // j*64 + i
        const int j = idx >> 6, i = idx & 63;
        const double v = (double)pm[h * 4096 + idx];
        Mc[j * 65 + i] = v;
        Ac[j * 65 + i] = v;
    }

    // ---- factor: 64 Householder steps, LAPACK dlarfg semantics ----
    for (int j = 0; j < 64; ++j) {
        __syncthreads();                          // prior updates visible
        if (tid < 64) {
            const int i = tid;
            const double a = Ac[j * 65 + i];
            double t = (i > j) ? a * a : 0.0;
            #pragma unroll
            for (int m = 1; m < 64; m <<= 1) t += __shfl_xor(t, m);
            const double alpha = __shfl(a, j);
            double v, tau, beta;
            if (t == 0.0) {                       // xnorm==0 -> H=I, tau=0
                tau = 0.0; beta = alpha;
                v = (i == j) ? 1.0 : 0.0;
            } else {
                const double anorm = sqrt(alpha * alpha + t);
                beta = (alpha >= 0.0) ? -anorm : anorm;
                tau  = (beta - alpha) / beta;
                const double scale = 1.0 / (alpha - beta);
                v = (i == j) ? 1.0 : ((i > j) ? a * scale : 0.0);
            }
            vs[i] = v;
            if (i == j) { Ac[j * 65 + j] = beta; tau_s = tau; }
        }
        __syncthreads();
        if (c > j) {                              // w partial: V^T * A[:,c]
            double w = 0.0;
            #pragma unroll
            for (int k = 0; k < 16; ++k)          // vs[i]=0 for i<j masks
                w = fma(vs[i0 + k], Ac[c * 65 + i0 + k], w);
            Ws[q * 64 + c] = w;
        }
        __syncthreads();
        if (c > j) {                              // rank-1 update
            const double tw = tau_s *
                ((Ws[c] + Ws[64 + c]) + (Ws[128 + c] + Ws[192 + c]));
            #pragma unroll
            for (int k = 0; k < 16; ++k)
                Ac[c * 65 + i0 + k] =
                    fma(-tw, vs[i0 + k], Ac[c * 65 + i0 + k]);
        }
    }

    // ---- solve Q R = M (forward column sweep, 1 barrier/step) ----
    // Q[:,j] = Mcur[:,j]/R[j,j]; Mcur[:,c>j] -= Mcur[:,j]*(R[j,c]/R[j,j])
    for (int j = 0; j < 64; ++j) {
        __syncthreads();
        const double inv = 1.0 / Ac[j * 65 + j];  // R[j,j] (signed beta)
        if (tid < 64) Qc[j * 65 + tid] = Mc[j * 65 + tid] * inv;
        if (c > j) {
            const double f = Ac[c * 65 + j] * inv;     // R[j,c]/R[j,j]
            #pragma unroll
            for (int k = 0; k < 16; ++k)
                Mc[c * 65 + i0 + k] =
                    fma(-Mc[j * 65 + i0 + k], f, Mc[c * 65 + i0 + k]);
        }
    }
    __syncthreads();

    // ---- proj[e][f] = Q[f][e] * sign(beta_f); fold normalizer 2^-1.5 ----
    const double nz = 0.35355339059327373;
    #pragma unroll
    for (int kk = 0; kk < 16; ++kk) {
        const int idx = tid + 256 * kk;           // e*64 + f
        const int e = idx >> 6, f = idx & 63;
        const double s = (Ac[f * 65 + f] >= 0.0) ? nz : -nz;
        P[h * 4096 + idx] = (float)(Qc[e * 65 + f] * s);
    }
}

// ---------------- main FAVOR+ map: 4x4 register-tiled -----------------------
__device__ __forceinline__ float4 f4fma(float s, float4 a, float4 b) {
    return make_float4(fmaf(s, a.x, b.x), fmaf(s, a.y, b.y),
                       fmaf(s, a.z, b.z), fmaf(s, a.w, b.w));
}

__global__ __launch_bounds__(256) void favor_kernel(const float* __restrict__ data,
                                                    const float* __restrict__ P,
                                                    float* __restrict__ out)
{
    __shared__ float Xs[64 * 68];    // X tile row-major, padded: Xs[r*68+e]
    __shared__ float Ps[64 * 68];    // P head: Ps[e*68+f]
    __shared__ float sq_s[64];

    const int tid = threadIdx.x;
    const int h   = blockIdx.x & 15;
    const size_t chunk = blockIdx.x >> 4;      // 0..63
    const int fi = tid & 15;                   // feature quad: f0 = 4*fi
    const int ri = tid >> 4;                   // row quad:     r0 = 4*ri
    const int f0 = fi * 4;
    const int r0 = ri * 4;

    // stage P head (4096 floats) once
    #pragma unroll
    for (int k = 0; k < 4; ++k) {
        const int i4 = tid + 256 * k;          // float4 id 0..1023
        const int e = i4 >> 4, cc = i4 & 15;
        const float4 v = reinterpret_cast<const float4*>(P)[h * 1024 + i4];
        *reinterpret_cast<float4*>(&Ps[e * 68 + 4 * cc]) = v;
    }

    const size_t row0 = chunk * 1024;          // 1024 rows per block, 16 tiles

    for (int t = 0; t < 16; ++t) {
        const size_t rbase = row0 + (size_t)t * 64;
        __syncthreads();                       // Xs safe to overwrite (+P vis)
        // ---- stage 64 rows (no transpose) + 0.5*||x||^2 ----
        #pragma unroll
        for (int k = 0; k < 4; ++k) {
            const int i4 = tid + 256 * k;      // 0..1023
            const int r = i4 >> 4, cc = i4 & 15;
            const size_t row = rbase + (size_t)r;
            const float4 v = reinterpret_cast<const float4*>(data)[row * 256 + h * 16 + cc];
            *reinterpret_cast<float4*>(&Xs[r * 68 + 4 * cc]) = v;
            float sqp = v.x * v.x + v.y * v.y + v.z * v.z + v.w * v.w;
            sqp += __shfl_xor(sqp, 1);
            sqp += __shfl_xor(sqp, 2);
            sqp += __shfl_xor(sqp, 4);
            sqp += __shfl_xor(sqp, 8);
            if (cc == 0) sq_s[r] = 0.0625f * sqp;   // 0.5 * nz^2 = 1/16
        }
        __syncthreads();
        // ---- 4 rows x 4 features per thread ----
        float4 acc0 = {0,0,0,0}, acc1 = {0,0,0,0},
               acc2 = {0,0,0,0}, acc3 = {0,0,0,0};
        #pragma unroll
        for (int eq = 0; eq < 16; ++eq) {
            const int e0 = eq * 4;
            const float4 xa = *reinterpret_cast<const float4*>(&Xs[(r0 + 0) * 68 + e0]);
            const float4 xb = *reinterpret_cast<const float4*>(&Xs[(r0 + 1) * 68 + e0]);
            const float4 xc = *reinterpret_cast<const float4*>(&Xs[(r0 + 2) * 68 + e0]);
            const float4 xd = *reinterpret_cast<const float4*>(&Xs[(r0 + 3) * 68 + e0]);
            const float4 pa = *reinterpret_cast<const float4*>(&Ps[(e0 + 0) * 68 + f0]);
            const float4 pb = *reinterpret_cast<const float4*>(&Ps[(e0 + 1) * 68 + f0]);
            const float4 pc = *reinterpret_cast<const float4*>(&Ps[(e0 + 2) * 68 + f0]);
            const float4 pd = *reinterpret_cast<const float4*>(&Ps[(e0 + 3) * 68 + f0]);
            acc0 = f4fma(xa.x, pa, acc0); acc0 = f4fma(xa.y, pb, acc0);
            acc0 = f4fma(xa.z, pc, acc0); acc0 = f4fma(xa.w, pd, acc0);
            acc1 = f4fma(xb.x, pa, acc1); acc1 = f4fma(xb.y, pb, acc1);
            acc1 = f4fma(xb.z, pc, acc1); acc1 = f4fma(xb.w, pd, acc1);
            acc2 = f4fma(xc.x, pa, acc2); acc2 = f4fma(xc.y, pb, acc2);
            acc2 = f4fma(xc.z, pc, acc2); acc2 = f4fma(xc.w, pd, acc2);
            acc3 = f4fma(xd.x, pa, acc3); acc3 = f4fma(xd.y, pb, acc3);
            acc3 = f4fma(xd.z, pc, acc3); acc3 = f4fma(xd.w, pd, acc3);
        }
        const float4 sq4 = *reinterpret_cast<const float4*>(&sq_s[r0]);
        const size_t orow = (rbase + (size_t)r0) * 16 + (size_t)h; // in 64-float units
        float4* out4 = reinterpret_cast<float4*>(out);
        float4 o;
        o.x = __expf(acc0.x - sq4.x) + 1e-6f; o.y = __expf(acc0.y - sq4.x) + 1e-6f;
        o.z = __expf(acc0.z - sq4.x) + 1e-6f; o.w = __expf(acc0.w - sq4.x) + 1e-6f;
        out4[(orow      ) * 16 + fi] = o;
        o.x = __expf(acc1.x - sq4.y) + 1e-6f; o.y = __expf(acc1.y - sq4.y) + 1e-6f;
        o.z = __expf(acc1.z - sq4.y) + 1e-6f; o.w = __expf(acc1.w - sq4.y) + 1e-6f;
        out4[(orow +  16) * 16 + fi] = o;
        o.x = __expf(acc2.x - sq4.z) + 1e-6f; o.y = __expf(acc2.y - sq4.z) + 1e-6f;
        o.z = __expf(acc2.z - sq4.z) + 1e-6f; o.w = __expf(acc2.w - sq4.z) + 1e-6f;
        out4[(orow +  32) * 16 + fi] = o;
        o.x = __expf(acc3.x - sq4.w) + 1e-6f; o.y = __expf(acc3.y - sq4.w) + 1e-6f;
        o.z = __expf(acc3.z - sq4.w) + 1e-6f; o.w = __expf(acc3.w - sq4.w) + 1e-6f;
        out4[(orow +  48) * 16 + fi] = o;
    }
}

extern "C" void kernel_launch(void* const* d_in, const int* in_sizes, int n_in,
                              void* d_out, int out_size, void* d_ws, size_t ws_size,
                              hipStream_t stream)
{
    const float* data = (const float*)d_in[0];   // (L,N,H,E) fp32
    const float* pm   = (const float*)d_in[1];   // (H,E,E)   fp32
    float* out = (float*)d_out;                  // (L,N,H,F) fp32
    float* P   = (float*)d_ws;                   // 16*64*64*4 = 256 KB scratch

    qr_kernel<<<16, 256, 0, stream>>>(pm, P);
    favor_kernel<<<1024, 256, 0, stream>>>(data, P, out);
}